// Round 13
// baseline (241.161 us; speedup 1.0000x reference)
//
#include <hip/hip_runtime.h>

constexpr int BATCH = 2048;
constexpr int NHID  = 512;
constexpr int H0    = 256;
constexpr int H1    = 256;
constexpr int SMAX  = 32;          // samples per tile (P(n>32) ~ 1e-11)
constexpr int NKC   = 8;           // K chunks of 64 (2 MFMA k-groups each)

typedef __attribute__((ext_vector_type(8))) short short8v;  // bf16x8 frag
typedef __attribute__((ext_vector_type(4))) float f32x4;    // MFMA acc

static __device__ __forceinline__ unsigned short bf_hi(float f) {
    return (unsigned short)(__float_as_uint(f) >> 16);       // truncate
}
static __device__ __forceinline__ float bf_f(unsigned short h) {
    return __uint_as_float(((unsigned int)h) << 16);
}

// One block per parent p (grid = 256 = #CUs), 1024 thr = 16 waves (4/SIMD).
// r12 design (verified: absmax 4.8e-7, no spill, direct global->reg B path)
// with KC 32 -> 64: per chunk, convert BOTH k-groups' B frags (freeing bx),
// THEN issue next chunk's 32 loads, THEN 24 MFMA + A reads. Issue-to-use
// cover ~350 own-cyc x 4 waves/SIMD ~ 1400 cyc > 900-cyc HBM miss (r12's
// 1-deep/32-row pipeline covered only ~600 -> per-chunk stalls = the gap).
// Wave g<8: bottom cols 32g..+31 (tiles 2g,2g+1); g>=8: same cols of top.
__global__ __launch_bounds__(1024) void hs_mfma3(
    const float* __restrict__ x,        // [B, NHID]
    const int*   __restrict__ labels,   // [B]
    const int*   __restrict__ parents,  // [B]
    const float* __restrict__ topW,     // [NHID, H0]
    const float* __restrict__ topb,     // [H0]
    const float* __restrict__ botW,     // [H0, NHID, H1]
    const float* __restrict__ botb,     // [H0, H1]
    float*       __restrict__ out)      // [B]
{
    const int p  = blockIdx.x;
    const int t  = threadIdx.x;        // 0..1023
    const int g  = t >> 6;             // wave 0..15
    const int l  = t & 63;
    const int lh = l >> 4;             // 0..3
    const int li = l & 15;

    __shared__ int list[BATCH];                 // 8 KB
    __shared__ int wcnt[16];
    // A hi (32KB) + A lo (32KB) + pad; logits [32][512] f32 overlay after K.
    __shared__ __align__(16) char AL[81920];
    float* Lg = (float*)AL;

    // ---- deterministic list build (verified ballot scan, 16-wave form)
    int running = 0;
    for (int c = 0; c < BATCH; c += 1024) {
        const bool match = (parents[c + t] == p);
        const unsigned long long mask = __ballot(match);
        if (l == 0) wcnt[g] = __popcll(mask);
        __syncthreads();
        int off = running;
        #pragma unroll
        for (int w = 0; w < 16; ++w) {
            const int cw = wcnt[w];
            if (w < g) off += cw;
            running += cw;
        }
        if (match)
            list[off + __popcll(mask & ((1ull << l) - 1ull))] = c + t;
        __syncthreads();
    }
    const int n = running;
    if (n == 0) return;    // block-uniform exit

    const float4 bb = *(const float4*)(botb + (size_t)p * H1 + 4 * l);
    const float4 bt = *(const float4*)(topb + 4 * l);

    const bool bot = (g < 8);
    const int  wv  = g & 7;
    const float* Wsrc = bot ? botW + (size_t)p * NHID * H1 : topW;
    const int colL = 32 * wv + li;     // lane col (2nd tile adds 16)

    for (int base = 0; base < n; base += SMAX) {    // ~always 1 iteration
        const int rem = min(SMAX, n - base);

        // ---- A stage (threads 0..511; verified layout & swizzle)
        if (t < 512) {
            const int s  = t >> 4;
            const int c0 = 32 * (t & 15);
            const float* xr =
                x + (size_t)list[base + min(s, rem - 1)] * NHID + c0;
            #pragma unroll
            for (int b = 0; b < 4; ++b) {
                const float4 v0 = ((const float4*)xr)[2 * b];
                const float4 v1 = ((const float4*)xr)[2 * b + 1];
                const float fe[8] = {v0.x, v0.y, v0.z, v0.w,
                                     v1.x, v1.y, v1.z, v1.w};
                short8v hv, lv;
                #pragma unroll
                for (int e = 0; e < 8; ++e) {
                    const unsigned short h = bf_hi(fe[e]);
                    hv[e] = (short)h;
                    lv[e] = (short)bf_hi(fe[e] - bf_f(h));
                }
                const int byte = ((s * NHID + c0 + 8 * b) * 2) ^ ((s & 7) << 4);
                *(short8v*)(AL + byte)         = hv;   // A hi
                *(short8v*)(AL + 32768 + byte) = lv;   // A lo
            }
        }
        __syncthreads();   // A visible to all waves

        f32x4 acc[2][2];   // [tile][row-tile], static indices only
        #pragma unroll
        for (int tt = 0; tt < 2; ++tt)
            #pragma unroll
            for (int r = 0; r < 2; ++r) acc[tt][r] = (f32x4)(0.0f);

        // ---- prologue: chunk 0 (64 rows, both k-groups) -> regs
        float bx0[16], bx1[16];
        #pragma unroll
        for (int e = 0; e < 16; ++e) {
            const int row = (e < 8) ? (8 * lh + e) : (32 + 8 * lh + (e - 8));
            const size_t rowb = (size_t)row * 256;
            bx0[e] = Wsrc[rowb + colL];
            bx1[e] = Wsrc[rowb + colL + 16];
        }

        for (int kc = 0; kc < NKC; ++kc) {
            // convert BOTH k-groups' B frags (frees bx0/bx1)
            short8v bh0a, bl0a, bh1a, bl1a;   // k-group a (rows +0)
            short8v bh0b, bl0b, bh1b, bl1b;   // k-group b (rows +32)
            #pragma unroll
            for (int e = 0; e < 8; ++e) {
                unsigned short h;
                h = bf_hi(bx0[e]);     bh0a[e] = (short)h;
                bl0a[e] = (short)bf_hi(bx0[e] - bf_f(h));
                h = bf_hi(bx1[e]);     bh1a[e] = (short)h;
                bl1a[e] = (short)bf_hi(bx1[e] - bf_f(h));
                h = bf_hi(bx0[8 + e]); bh0b[e] = (short)h;
                bl0b[e] = (short)bf_hi(bx0[8 + e] - bf_f(h));
                h = bf_hi(bx1[8 + e]); bh1b[e] = (short)h;
                bl1b[e] = (short)bf_hi(bx1[8 + e] - bf_f(h));
            }

            // issue next chunk's loads NOW (fly under 24 MFMA + A reads)
            if (kc + 1 < NKC) {
                const int kb = (kc + 1) * 64;
                #pragma unroll
                for (int e = 0; e < 16; ++e) {
                    const int row = kb + ((e < 8) ? (8 * lh + e)
                                                  : (32 + 8 * lh + (e - 8)));
                    const size_t rowb = (size_t)row * 256;
                    bx0[e] = Wsrc[rowb + colL];
                    bx1[e] = Wsrc[rowb + colL + 16];
                }
            }

            // ---- k-group a: K0 = 64*kc
            {
                const int K0 = 64 * kc;
                short8v afh[2], afl[2];
                #pragma unroll
                for (int r = 0; r < 2; ++r) {
                    const int arow = 16 * r + li;
                    const int ab   = ((arow * NHID + K0 + lh * 8) * 2)
                                     ^ ((arow & 7) << 4);
                    afh[r] = *(const short8v*)(AL + ab);
                    afl[r] = *(const short8v*)(AL + 32768 + ab);
                }
                #pragma unroll
                for (int r = 0; r < 2; ++r) {
                    acc[0][r] = __builtin_amdgcn_mfma_f32_16x16x32_bf16(
                                    afh[r], bh0a, acc[0][r], 0, 0, 0);
                    acc[0][r] = __builtin_amdgcn_mfma_f32_16x16x32_bf16(
                                    afl[r], bh0a, acc[0][r], 0, 0, 0);
                    acc[0][r] = __builtin_amdgcn_mfma_f32_16x16x32_bf16(
                                    afh[r], bl0a, acc[0][r], 0, 0, 0);
                    acc[1][r] = __builtin_amdgcn_mfma_f32_16x16x32_bf16(
                                    afh[r], bh1a, acc[1][r], 0, 0, 0);
                    acc[1][r] = __builtin_amdgcn_mfma_f32_16x16x32_bf16(
                                    afl[r], bh1a, acc[1][r], 0, 0, 0);
                    acc[1][r] = __builtin_amdgcn_mfma_f32_16x16x32_bf16(
                                    afh[r], bl1a, acc[1][r], 0, 0, 0);
                }
            }
            // ---- k-group b: K0 = 64*kc + 32
            {
                const int K0 = 64 * kc + 32;
                short8v afh[2], afl[2];
                #pragma unroll
                for (int r = 0; r < 2; ++r) {
                    const int arow = 16 * r + li;
                    const int ab   = ((arow * NHID + K0 + lh * 8) * 2)
                                     ^ ((arow & 7) << 4);
                    afh[r] = *(const short8v*)(AL + ab);
                    afl[r] = *(const short8v*)(AL + 32768 + ab);
                }
                #pragma unroll
                for (int r = 0; r < 2; ++r) {
                    acc[0][r] = __builtin_amdgcn_mfma_f32_16x16x32_bf16(
                                    afh[r], bh0b, acc[0][r], 0, 0, 0);
                    acc[0][r] = __builtin_amdgcn_mfma_f32_16x16x32_bf16(
                                    afl[r], bh0b, acc[0][r], 0, 0, 0);
                    acc[0][r] = __builtin_amdgcn_mfma_f32_16x16x32_bf16(
                                    afh[r], bl0b, acc[0][r], 0, 0, 0);
                    acc[1][r] = __builtin_amdgcn_mfma_f32_16x16x32_bf16(
                                    afh[r], bh1b, acc[1][r], 0, 0, 0);
                    acc[1][r] = __builtin_amdgcn_mfma_f32_16x16x32_bf16(
                                    afl[r], bh1b, acc[1][r], 0, 0, 0);
                    acc[1][r] = __builtin_amdgcn_mfma_f32_16x16x32_bf16(
                                    afh[r], bl1b, acc[1][r], 0, 0, 0);
                }
            }
        }
        __syncthreads();   // all A reads done -> AL reusable as logits

        // ---- D -> logits (verified mapping: col=li, row=lh*4+j)
        const int cg = (bot ? 0 : 256) + 32 * wv;
        #pragma unroll
        for (int tt = 0; tt < 2; ++tt) {
            #pragma unroll
            for (int r = 0; r < 2; ++r) {
                #pragma unroll
                for (int j = 0; j < 4; ++j) {
                    const int row = 16 * r + lh * 4 + j;
                    Lg[row * NHID + cg + 16 * tt + li] = acc[tt][r][j];
                }
            }
        }
        __syncthreads();   // logits complete

        // ---- two softmaxes per sample (verified); waves 0-7 only
        if (g < 8) {
            #pragma unroll
            for (int i2 = 0; i2 < 4; ++i2) {
                const int s = 4 * g + i2;
                if (s < rem) {               // wave-uniform
                    const int idx = list[base + s];
                    const float* Lrow = Lg + s * NHID;

                    float4 v = *(const float4*)(Lrow + 4 * l);
                    v.x += bb.x; v.y += bb.y; v.z += bb.z; v.w += bb.w;
                    float m = fmaxf(fmaxf(v.x, v.y), fmaxf(v.z, v.w));
                    #pragma unroll
                    for (int off = 32; off > 0; off >>= 1)
                        m = fmaxf(m, __shfl_xor(m, off, 64));
                    const float ex = expf(v.x - m), ey = expf(v.y - m);
                    const float ez = expf(v.z - m), ew = expf(v.w - m);
                    float sum = (ex + ey) + (ez + ew);
                    #pragma unroll
                    for (int off = 32; off > 0; off >>= 1)
                        sum += __shfl_xor(sum, off, 64);
                    const int tb_ = labels[idx];
                    const int kb_ = tb_ & 3;
                    const float evb = (kb_ == 0) ? ex : (kb_ == 1) ? ey
                                    : (kb_ == 2) ? ez : ew;
                    const float pb = __shfl(evb / sum, tb_ >> 2, 64);

                    float4 u = *(const float4*)(Lrow + 256 + 4 * l);
                    u.x += bt.x; u.y += bt.y; u.z += bt.z; u.w += bt.w;
                    float mu = fmaxf(fmaxf(u.x, u.y), fmaxf(u.z, u.w));
                    #pragma unroll
                    for (int off = 32; off > 0; off >>= 1)
                        mu = fmaxf(mu, __shfl_xor(mu, off, 64));
                    const float tx = expf(u.x - mu), ty = expf(u.y - mu);
                    const float tz = expf(u.z - mu), tw = expf(u.w - mu);
                    float tsum = (tx + ty) + (tz + tw);
                    #pragma unroll
                    for (int off = 32; off > 0; off >>= 1)
                        tsum += __shfl_xor(tsum, off, 64);
                    const int kt_ = p & 3;
                    const float evt = (kt_ == 0) ? tx : (kt_ == 1) ? ty
                                    : (kt_ == 2) ? tz : tw;
                    const float pt = __shfl(evt / tsum, p >> 2, 64);

                    if (l == 0) out[idx] = pt * pb;
                }
            }
        }
        __syncthreads();   // AL reusable (A restage) next tile
    }
}

extern "C" void kernel_launch(void* const* d_in, const int* in_sizes, int n_in,
                              void* d_out, int out_size, void* d_ws, size_t ws_size,
                              hipStream_t stream) {
    const float* x       = (const float*)d_in[0];
    const int*   labels  = (const int*)  d_in[1];
    const int*   parents = (const int*)  d_in[2];
    const float* topW    = (const float*)d_in[3];
    const float* topb    = (const float*)d_in[4];
    const float* botW    = (const float*)d_in[5];
    const float* botb    = (const float*)d_in[6];
    float*       out     = (float*)d_out;

    hs_mfma3<<<H0, 1024, 0, stream>>>(x, labels, parents,
                                      topW, topb, botW, botb, out);
}